// Round 6
// baseline (647.080 us; speedup 1.0000x reference)
//
#include <hip/hip_runtime.h>
#include <math.h>

typedef short bf16x8 __attribute__((ext_vector_type(8)));
typedef float f32x4 __attribute__((ext_vector_type(4)));

__device__ __forceinline__ ushort f2bf(float f) {
  union { float f; unsigned int i; } v; v.f = f;
  unsigned int x = v.i;
  return (ushort)((x + 0x7fffu + ((x >> 16) & 1u)) >> 16);  // RNE
}
__device__ __forceinline__ float bf2f(ushort u) {
  union { unsigned int i; float f; } v; v.i = ((unsigned int)u) << 16; return v.f;
}
// packed helpers: dword holds 2 bf16 (lo = even tok, hi = odd tok)
__device__ __forceinline__ float bfLo(unsigned int d) {
  union { unsigned int i; float f; } v; v.i = d << 16; return v.f;
}
__device__ __forceinline__ float bfHi(unsigned int d) {
  union { unsigned int i; float f; } v; v.i = d & 0xffff0000u; return v.f;
}

// ---------------- pre-kernel: swizzle weights to B-fragment tiles ----------
// tile = 16 cols x 32 k = 64 lanes x 8 bf16 (lane holds B[k0+(l>>4)*8+j][n0+(l&15)])
// d_ws tiles: [0,54) qkv (3 chunks x 6nt x 3kt), [54,72) merge, [72,90) w1a,
// [90,108) w1b (k offset 96), [108,126) w2.  126 tiles x 1024 B = 129024 B.
__global__ void swizzle_w(const float* __restrict__ qkv_w,
                          const float* __restrict__ merge_w,
                          const float* __restrict__ w1,
                          const float* __restrict__ w2,
                          ushort* __restrict__ ws) {
  int g = blockIdx.x * 256 + threadIdx.x;
  if (g >= 8064) return;  // 126 tiles * 64 lanes
  int tile = g >> 6, lane = g & 63;
  const float* src; int ld, c0, k0, rem;
  if (tile < 54)       { rem = tile % 18; src = qkv_w;   ld = 288; c0 = (tile / 18) * 96 + (rem / 3) * 16; k0 = (rem % 3) * 32; }
  else if (tile < 72)  { rem = tile - 54; src = merge_w; ld = 96;  c0 = (rem / 3) * 16; k0 = (rem % 3) * 32; }
  else if (tile < 90)  { rem = tile - 72; src = w1;      ld = 96;  c0 = (rem / 3) * 16; k0 = (rem % 3) * 32; }
  else if (tile < 108) { rem = tile - 90; src = w1;      ld = 96;  c0 = (rem / 3) * 16; k0 = 96 + (rem % 3) * 32; }
  else                 { rem = tile - 108; src = w2;     ld = 96;  c0 = (rem / 3) * 16; k0 = (rem % 3) * 32; }
  int n = c0 + (lane & 15);
  int kb = k0 + (lane >> 4) * 8;
  ushort tmp[8];
#pragma unroll
  for (int j = 0; j < 8; ++j) tmp[j] = f2bf(src[(size_t)(kb + j) * ld + n]);
  *(uint4*)(ws + tile * 512 + lane * 8) = *(const uint4*)tmp;
}

// ---------------- main fused kernel ----------------------------------------
// block: 64 tokens = (2h x 2w) x 16t = 8 windows along t. 4 waves, wave w owns
// tokens [16w,16w+16). Weights direct from global (wsw, L2-resident).
// CHANGE vs round 5: Xs eliminated. X is staged into R's region (R is dead
// before P2), each wave reads its A-fragments (aX) into registers ONCE and
// holds them through P5 (aX2 was the same data). One extra barrier guards the
// aX reads before QKV overwrites R. LDS 52736 -> 39424 B => 4 blocks/CU.
#define KPAD 104
#define QPAD 68   // QKV [col 0..287][tok]; 68*2B=136B stride; all P3 read
                  // offsets are multiples of 4 ushorts (8B) -> uint2-safe
#define OPAD 65   // out [col 0..95][tok] stride
__global__ __launch_bounds__(256, 4) void swin_mfma(
    const float* __restrict__ x,
    const float* __restrict__ qkv_b, const float* __restrict__ merge_b,
    const float* __restrict__ b1, const float* __restrict__ b2,
    const ushort* __restrict__ wsw, float* __restrict__ out) {
  __shared__ __align__(16) ushort R[288 * QPAD];   // 39168 B: X -> QKV -> msg/hmid/out

  const int tid = threadIdx.x, bid = blockIdx.x;
  const int t0 = bid & 3, w0 = (bid >> 2) & 31, h0 = (bid >> 7) & 31, b = bid >> 12;
  const int lane = tid & 63, wave = tid >> 6;
  const int mrow = lane & 15, quad = lane >> 4;
  const int arow = (wave * 16 + mrow) * KPAD + quad * 8;  // A-frag base (elems)
  const int tokb = wave * 16 + quad * 4;                  // C-frag row base

  // P1: x -> R[tok*KPAD + c] bf16 (coalesced float4 along t); R dead until P2
  for (int i = tid; i < 1536; i += 256) {
    int q = i & 3, dw = (i >> 2) & 1, dh = (i >> 3) & 1, c = i >> 4;
    size_t g = ((((size_t)b * 96 + c) * 64 + h0 * 2 + dh) * 64 + w0 * 2 + dw) * 64 + t0 * 16 + q * 4;
    float4 v = *(const float4*)(x + g);
    float vv[4] = {v.x, v.y, v.z, v.w};
    int base = dh * 4 + dw * 2;
#pragma unroll
    for (int j = 0; j < 4; ++j) {
      int tl = q * 4 + j;
      R[((tl >> 1) * 8 + base + (tl & 1)) * KPAD + c] = f2bf(vv[j]);
    }
  }
  __syncthreads();  // (1a) X staged cross-thread

  bf16x8 aX[3];     // held in registers through P5 (was Xs/aX2)
#pragma unroll
  for (int kt = 0; kt < 3; ++kt)
    aX[kt] = *(const bf16x8*)(R + arow + kt * 32);
  __syncthreads();  // (1b) ALL waves' aX reads done before QKV overwrites R

  // P2: QKV (3 chunks of 96 cols) -> R[col][tok] stride QPAD
  for (int cn = 0; cn < 3; ++cn) {
#pragma unroll
    for (int nt = 0; nt < 6; ++nt) {
      int col = cn * 96 + nt * 16 + mrow;
      float bias = qkv_b[col];
      f32x4 acc = {bias, bias, bias, bias};
#pragma unroll
      for (int kt = 0; kt < 3; ++kt) {
        bf16x8 bf = *(const bf16x8*)(wsw + (size_t)(cn * 18 + nt * 3 + kt) * 512 + lane * 8);
        acc = __builtin_amdgcn_mfma_f32_16x16x32_bf16(aX[kt], bf, acc, 0, 0, 0);
      }
#pragma unroll
      for (int r = 0; r < 4; ++r) R[col * QPAD + tokb + r] = f2bf(acc[r]);
    }
  }
  __syncthreads();  // (2) QKV complete

  // P3: attention. thread = (win, head, 2 query rows). Q cols 0..95, K 96.., V 192..
  // Packed reads: tok pairs (2t, 2t+1) share one dword (lo=even, hi=odd).
  {
    const int win = tid >> 5, head = (tid >> 2) & 7, r2 = (tid & 3) * 2;
    const ushort* Qb = R + (head * 12) * QPAD + win * 8;
    const ushort* Kb = R + (96 + head * 12) * QPAD + win * 8;
    const ushort* Vb = R + (192 + head * 12) * QPAD + win * 8;
    const float scale = 0.28867513459481287f;  // 1/sqrt(12), folded into q
    float q0[12], q1[12];
#pragma unroll
    for (int d = 0; d < 12; ++d) {
      unsigned int qq = *(const unsigned int*)(Qb + d * QPAD + r2);  // rows r2,r2+1
      q0[d] = bfLo(qq) * scale;
      q1[d] = bfHi(qq) * scale;
    }
    float s0[8] = {0, 0, 0, 0, 0, 0, 0, 0}, s1[8] = {0, 0, 0, 0, 0, 0, 0, 0};
#pragma unroll
    for (int d = 0; d < 12; ++d) {  // K column d: all 8 window toks in 2 b64s
      uint2 ka = *(const uint2*)(Kb + d * QPAD);
      uint2 kc = *(const uint2*)(Kb + d * QPAD + 4);
      float kf[8] = {bfLo(ka.x), bfHi(ka.x), bfLo(ka.y), bfHi(ka.y),
                     bfLo(kc.x), bfHi(kc.x), bfLo(kc.y), bfHi(kc.y)};
#pragma unroll
      for (int m = 0; m < 8; ++m) { s0[m] += q0[d] * kf[m]; s1[m] += q1[d] * kf[m]; }
    }
    float mx0 = fmaxf(fmaxf(fmaxf(s0[0], s0[1]), fmaxf(s0[2], s0[3])),
                      fmaxf(fmaxf(s0[4], s0[5]), fmaxf(s0[6], s0[7])));
    float mx1 = fmaxf(fmaxf(fmaxf(s1[0], s1[1]), fmaxf(s1[2], s1[3])),
                      fmaxf(fmaxf(s1[4], s1[5]), fmaxf(s1[6], s1[7])));
    float sum0 = 0.f, sum1 = 0.f;
#pragma unroll
    for (int m = 0; m < 8; ++m) {
      s0[m] = __expf(s0[m] - mx0); sum0 += s0[m];
      s1[m] = __expf(s1[m] - mx1); sum1 += s1[m];
    }
    float inv0 = 1.0f / sum0, inv1 = 1.0f / sum1;
    float o0[12], o1[12];
#pragma unroll
    for (int d = 0; d < 12; ++d) {  // V column d, normalize at the end
      uint2 va = *(const uint2*)(Vb + d * QPAD);
      uint2 vc = *(const uint2*)(Vb + d * QPAD + 4);
      float vf[8] = {bfLo(va.x), bfHi(va.x), bfLo(va.y), bfHi(va.y),
                     bfLo(vc.x), bfHi(vc.x), bfLo(vc.y), bfHi(vc.y)};
      float a0 = 0.f, a1 = 0.f;
#pragma unroll
      for (int m = 0; m < 8; ++m) { a0 += s0[m] * vf[m]; a1 += s1[m] * vf[m]; }
      o0[d] = a0 * inv0; o1[d] = a1 * inv1;
    }
    __syncthreads();  // (3) ALL QKV reads complete before msg overwrites R
    int tr = win * 8 + r2;
#pragma unroll
    for (int d = 0; d < 12; ++d) {
      R[tr * KPAD + head * 12 + d] = f2bf(o0[d]);
      R[(tr + 1) * KPAD + head * 12 + d] = f2bf(o1[d]);
    }
  }
  __syncthreads();  // (4) msg complete

  // P4: msg2 = msg @ merge_w + b  (in place; wave's rows only -> race-free)
  {
    bf16x8 aM[3];
#pragma unroll
    for (int kt = 0; kt < 3; ++kt) aM[kt] = *(const bf16x8*)(R + arow + kt * 32);
#pragma unroll
    for (int nt = 0; nt < 6; ++nt) {
      int col = nt * 16 + mrow;
      float bias = merge_b[col];
      f32x4 acc = {bias, bias, bias, bias};
#pragma unroll
      for (int kt = 0; kt < 3; ++kt) {
        bf16x8 bf = *(const bf16x8*)(wsw + (size_t)(54 + nt * 3 + kt) * 512 + lane * 8);
        acc = __builtin_amdgcn_mfma_f32_16x16x32_bf16(aM[kt], bf, acc, 0, 0, 0);
      }
#pragma unroll
      for (int r = 0; r < 4; ++r) R[(tokb + r) * KPAD + col] = f2bf(acc[r]);
    }
  }
  __syncthreads();  // (5) msg2 complete

  // P5: hmid = gelu(X@w1a + msg2@w1b + b1) -> R[6656 + tok*KPAD + col]
  // X A-fragments come from registers (aX) -- no LDS re-read.
  {
    bf16x8 aM2[3];
#pragma unroll
    for (int kt = 0; kt < 3; ++kt) aM2[kt] = *(const bf16x8*)(R + arow + kt * 32);
#pragma unroll
    for (int nt = 0; nt < 6; ++nt) {
      int col = nt * 16 + mrow;
      float bias = b1[col];
      f32x4 acc = {bias, bias, bias, bias};
#pragma unroll
      for (int kt = 0; kt < 3; ++kt) {
        bf16x8 bf = *(const bf16x8*)(wsw + (size_t)(72 + nt * 3 + kt) * 512 + lane * 8);
        acc = __builtin_amdgcn_mfma_f32_16x16x32_bf16(aX[kt], bf, acc, 0, 0, 0);
      }
#pragma unroll
      for (int kt = 0; kt < 3; ++kt) {
        bf16x8 bf = *(const bf16x8*)(wsw + (size_t)(90 + nt * 3 + kt) * 512 + lane * 8);
        acc = __builtin_amdgcn_mfma_f32_16x16x32_bf16(aM2[kt], bf, acc, 0, 0, 0);
      }
#pragma unroll
      for (int r = 0; r < 4; ++r) {
        float h = acc[r];
        float gel = 0.5f * h * (1.0f + erff(h * 0.70710678118654752f));
        R[6656 + (tokb + r) * KPAD + col] = f2bf(gel);
      }
    }
  }
  __syncthreads();  // (6) P6's out region overwrites other waves' msg2:
                    // all P5 msg2 reads must complete first

  // P6: out = hmid @ w2 + b2 -> R[col*OPAD + tok]  (over dead msg region)
  {
    bf16x8 aH[3];
#pragma unroll
    for (int kt = 0; kt < 3; ++kt) aH[kt] = *(const bf16x8*)(R + 6656 + arow + kt * 32);
#pragma unroll
    for (int nt = 0; nt < 6; ++nt) {
      int col = nt * 16 + mrow;
      float bias = b2[col];
      f32x4 acc = {bias, bias, bias, bias};
#pragma unroll
      for (int kt = 0; kt < 3; ++kt) {
        bf16x8 bf = *(const bf16x8*)(wsw + (size_t)(108 + nt * 3 + kt) * 512 + lane * 8);
        acc = __builtin_amdgcn_mfma_f32_16x16x32_bf16(aH[kt], bf, acc, 0, 0, 0);
      }
#pragma unroll
      for (int r = 0; r < 4; ++r) R[col * OPAD + tokb + r] = f2bf(acc[r]);
    }
  }
  __syncthreads();  // (7) out region read cross-wave in P7

  // P7: coalesced float4 store along t
  for (int i = tid; i < 1536; i += 256) {
    int q = i & 3, dw = (i >> 2) & 1, dh = (i >> 3) & 1, c = i >> 4;
    float vv[4];
#pragma unroll
    for (int j = 0; j < 4; ++j) {
      int tl = q * 4 + j;
      vv[j] = bf2f(R[c * OPAD + (tl >> 1) * 8 + dh * 4 + dw * 2 + (tl & 1)]);
    }
    float4 v = {vv[0], vv[1], vv[2], vv[3]};
    size_t g = ((((size_t)b * 96 + c) * 64 + h0 * 2 + dh) * 64 + w0 * 2 + dw) * 64 + t0 * 16 + q * 4;
    *(float4*)(out + g) = v;
  }
}

extern "C" void kernel_launch(void* const* d_in, const int* in_sizes, int n_in,
                              void* d_out, int out_size, void* d_ws, size_t ws_size,
                              hipStream_t stream) {
  const float* x = (const float*)d_in[0];
  const float* qkv_w = (const float*)d_in[1];
  const float* qkv_b = (const float*)d_in[2];
  const float* merge_w = (const float*)d_in[3];
  const float* merge_b = (const float*)d_in[4];
  const float* w1 = (const float*)d_in[5];
  const float* b1 = (const float*)d_in[6];
  const float* w2 = (const float*)d_in[7];
  const float* b2 = (const float*)d_in[8];
  ushort* wsw = (ushort*)d_ws;  // needs 129024 B
  swizzle_w<<<dim3(32), dim3(256), 0, stream>>>(qkv_w, merge_w, w1, w2, wsw);
  // grid: B(2) x h0(32) x w0(32) x t0(4) = 8192 blocks
  swin_mfma<<<dim3(8192), dim3(256), 0, stream>>>(
      x, qkv_b, merge_b, b1, b2, wsw, (float*)d_out);
}

// Round 7
// 556.217 us; speedup vs baseline: 1.1634x; 1.1634x over previous
//
#include <hip/hip_runtime.h>
#include <math.h>

typedef short bf16x8 __attribute__((ext_vector_type(8)));
typedef float f32x4 __attribute__((ext_vector_type(4)));

__device__ __forceinline__ ushort f2bf(float f) {
  union { float f; unsigned int i; } v; v.f = f;
  unsigned int x = v.i;
  return (ushort)((x + 0x7fffu + ((x >> 16) & 1u)) >> 16);  // RNE
}
__device__ __forceinline__ float bf2f(ushort u) {
  union { unsigned int i; float f; } v; v.i = ((unsigned int)u) << 16; return v.f;
}
// packed helpers: dword holds 2 bf16 (lo = even tok, hi = odd tok)
__device__ __forceinline__ float bfLo(unsigned int d) {
  union { unsigned int i; float f; } v; v.i = d << 16; return v.f;
}
__device__ __forceinline__ float bfHi(unsigned int d) {
  union { unsigned int i; float f; } v; v.i = d & 0xffff0000u; return v.f;
}

// ---------------- pre-kernel: swizzle weights to B-fragment tiles ----------
// tile = 16 cols x 32 k = 64 lanes x 8 bf16 (lane holds B[k0+(l>>4)*8+j][n0+(l&15)])
// d_ws tiles: [0,54) qkv (3 chunks x 6nt x 3kt), [54,72) merge, [72,90) w1a,
// [90,108) w1b (k offset 96), [108,126) w2.  126 tiles x 1024 B = 129024 B.
__global__ void swizzle_w(const float* __restrict__ qkv_w,
                          const float* __restrict__ merge_w,
                          const float* __restrict__ w1,
                          const float* __restrict__ w2,
                          ushort* __restrict__ ws) {
  int g = blockIdx.x * 256 + threadIdx.x;
  if (g >= 8064) return;  // 126 tiles * 64 lanes
  int tile = g >> 6, lane = g & 63;
  const float* src; int ld, c0, k0, rem;
  if (tile < 54)       { rem = tile % 18; src = qkv_w;   ld = 288; c0 = (tile / 18) * 96 + (rem / 3) * 16; k0 = (rem % 3) * 32; }
  else if (tile < 72)  { rem = tile - 54; src = merge_w; ld = 96;  c0 = (rem / 3) * 16; k0 = (rem % 3) * 32; }
  else if (tile < 90)  { rem = tile - 72; src = w1;      ld = 96;  c0 = (rem / 3) * 16; k0 = (rem % 3) * 32; }
  else if (tile < 108) { rem = tile - 90; src = w1;      ld = 96;  c0 = (rem / 3) * 16; k0 = 96 + (rem % 3) * 32; }
  else                 { rem = tile - 108; src = w2;     ld = 96;  c0 = (rem / 3) * 16; k0 = (rem % 3) * 32; }
  int n = c0 + (lane & 15);
  int kb = k0 + (lane >> 4) * 8;
  ushort tmp[8];
#pragma unroll
  for (int j = 0; j < 8; ++j) tmp[j] = f2bf(src[(size_t)(kb + j) * ld + n]);
  *(uint4*)(ws + tile * 512 + lane * 8) = *(const uint4*)tmp;
}

// ---------------- main fused kernel ----------------------------------------
// block: 64 tokens = (2h x 2w) x 16t = 8 windows along t. 4 waves, wave w owns
// tokens [16w,16w+16). Weights direct from global (wsw, L2-resident).
// Xs eliminated: X staged into R (dead before P2), aX held in registers
// through P5. LDS 39424 B => 4 blocks/CU by LDS.
// CHANGE vs round 6 (the ONLY change): __launch_bounds__ 4 -> 3. The (256,4)
// VGPR cap of 128 forced scratch spills (round-6 counters: +246 MB WRITE,
// +93 MB FETCH of spill traffic; MfmaUtil fell). Cap 168 lets the allocator
// fit aX's live range spill-free; expected usage ~90-110 still permits
// 4 waves/SIMD at runtime.
#define KPAD 104
#define QPAD 68   // QKV [col 0..287][tok]; 68*2B=136B stride; all P3 read
                  // offsets are multiples of 4 ushorts (8B) -> uint2-safe
#define OPAD 65   // out [col 0..95][tok] stride
__global__ __launch_bounds__(256, 3) void swin_mfma(
    const float* __restrict__ x,
    const float* __restrict__ qkv_b, const float* __restrict__ merge_b,
    const float* __restrict__ b1, const float* __restrict__ b2,
    const ushort* __restrict__ wsw, float* __restrict__ out) {
  __shared__ __align__(16) ushort R[288 * QPAD];   // 39168 B: X -> QKV -> msg/hmid/out

  const int tid = threadIdx.x, bid = blockIdx.x;
  const int t0 = bid & 3, w0 = (bid >> 2) & 31, h0 = (bid >> 7) & 31, b = bid >> 12;
  const int lane = tid & 63, wave = tid >> 6;
  const int mrow = lane & 15, quad = lane >> 4;
  const int arow = (wave * 16 + mrow) * KPAD + quad * 8;  // A-frag base (elems)
  const int tokb = wave * 16 + quad * 4;                  // C-frag row base

  // P1: x -> R[tok*KPAD + c] bf16 (coalesced float4 along t); R dead until P2
  for (int i = tid; i < 1536; i += 256) {
    int q = i & 3, dw = (i >> 2) & 1, dh = (i >> 3) & 1, c = i >> 4;
    size_t g = ((((size_t)b * 96 + c) * 64 + h0 * 2 + dh) * 64 + w0 * 2 + dw) * 64 + t0 * 16 + q * 4;
    float4 v = *(const float4*)(x + g);
    float vv[4] = {v.x, v.y, v.z, v.w};
    int base = dh * 4 + dw * 2;
#pragma unroll
    for (int j = 0; j < 4; ++j) {
      int tl = q * 4 + j;
      R[((tl >> 1) * 8 + base + (tl & 1)) * KPAD + c] = f2bf(vv[j]);
    }
  }
  __syncthreads();  // (1a) X staged cross-thread

  bf16x8 aX[3];     // held in registers through P5
#pragma unroll
  for (int kt = 0; kt < 3; ++kt)
    aX[kt] = *(const bf16x8*)(R + arow + kt * 32);
  __syncthreads();  // (1b) ALL waves' aX reads done before QKV overwrites R

  // P2: QKV (3 chunks of 96 cols) -> R[col][tok] stride QPAD
  for (int cn = 0; cn < 3; ++cn) {
#pragma unroll
    for (int nt = 0; nt < 6; ++nt) {
      int col = cn * 96 + nt * 16 + mrow;
      float bias = qkv_b[col];
      f32x4 acc = {bias, bias, bias, bias};
#pragma unroll
      for (int kt = 0; kt < 3; ++kt) {
        bf16x8 bf = *(const bf16x8*)(wsw + (size_t)(cn * 18 + nt * 3 + kt) * 512 + lane * 8);
        acc = __builtin_amdgcn_mfma_f32_16x16x32_bf16(aX[kt], bf, acc, 0, 0, 0);
      }
#pragma unroll
      for (int r = 0; r < 4; ++r) R[col * QPAD + tokb + r] = f2bf(acc[r]);
    }
  }
  __syncthreads();  // (2) QKV complete

  // P3: attention. thread = (win, head, 2 query rows). Q cols 0..95, K 96.., V 192..
  // Packed reads: tok pairs (2t, 2t+1) share one dword (lo=even, hi=odd).
  {
    const int win = tid >> 5, head = (tid >> 2) & 7, r2 = (tid & 3) * 2;
    const ushort* Qb = R + (head * 12) * QPAD + win * 8;
    const ushort* Kb = R + (96 + head * 12) * QPAD + win * 8;
    const ushort* Vb = R + (192 + head * 12) * QPAD + win * 8;
    const float scale = 0.28867513459481287f;  // 1/sqrt(12), folded into q
    float q0[12], q1[12];
#pragma unroll
    for (int d = 0; d < 12; ++d) {
      unsigned int qq = *(const unsigned int*)(Qb + d * QPAD + r2);  // rows r2,r2+1
      q0[d] = bfLo(qq) * scale;
      q1[d] = bfHi(qq) * scale;
    }
    float s0[8] = {0, 0, 0, 0, 0, 0, 0, 0}, s1[8] = {0, 0, 0, 0, 0, 0, 0, 0};
#pragma unroll
    for (int d = 0; d < 12; ++d) {  // K column d: all 8 window toks in 2 b64s
      uint2 ka = *(const uint2*)(Kb + d * QPAD);
      uint2 kc = *(const uint2*)(Kb + d * QPAD + 4);
      float kf[8] = {bfLo(ka.x), bfHi(ka.x), bfLo(ka.y), bfHi(ka.y),
                     bfLo(kc.x), bfHi(kc.x), bfLo(kc.y), bfHi(kc.y)};
#pragma unroll
      for (int m = 0; m < 8; ++m) { s0[m] += q0[d] * kf[m]; s1[m] += q1[d] * kf[m]; }
    }
    float mx0 = fmaxf(fmaxf(fmaxf(s0[0], s0[1]), fmaxf(s0[2], s0[3])),
                      fmaxf(fmaxf(s0[4], s0[5]), fmaxf(s0[6], s0[7])));
    float mx1 = fmaxf(fmaxf(fmaxf(s1[0], s1[1]), fmaxf(s1[2], s1[3])),
                      fmaxf(fmaxf(s1[4], s1[5]), fmaxf(s1[6], s1[7])));
    float sum0 = 0.f, sum1 = 0.f;
#pragma unroll
    for (int m = 0; m < 8; ++m) {
      s0[m] = __expf(s0[m] - mx0); sum0 += s0[m];
      s1[m] = __expf(s1[m] - mx1); sum1 += s1[m];
    }
    float inv0 = 1.0f / sum0, inv1 = 1.0f / sum1;
    float o0[12], o1[12];
#pragma unroll
    for (int d = 0; d < 12; ++d) {  // V column d, normalize at the end
      uint2 va = *(const uint2*)(Vb + d * QPAD);
      uint2 vc = *(const uint2*)(Vb + d * QPAD + 4);
      float vf[8] = {bfLo(va.x), bfHi(va.x), bfLo(va.y), bfHi(va.y),
                     bfLo(vc.x), bfHi(vc.x), bfLo(vc.y), bfHi(vc.y)};
      float a0 = 0.f, a1 = 0.f;
#pragma unroll
      for (int m = 0; m < 8; ++m) { a0 += s0[m] * vf[m]; a1 += s1[m] * vf[m]; }
      o0[d] = a0 * inv0; o1[d] = a1 * inv1;
    }
    __syncthreads();  // (3) ALL QKV reads complete before msg overwrites R
    int tr = win * 8 + r2;
#pragma unroll
    for (int d = 0; d < 12; ++d) {
      R[tr * KPAD + head * 12 + d] = f2bf(o0[d]);
      R[(tr + 1) * KPAD + head * 12 + d] = f2bf(o1[d]);
    }
  }
  __syncthreads();  // (4) msg complete

  // P4: msg2 = msg @ merge_w + b  (in place; wave's rows only -> race-free)
  {
    bf16x8 aM[3];
#pragma unroll
    for (int kt = 0; kt < 3; ++kt) aM[kt] = *(const bf16x8*)(R + arow + kt * 32);
#pragma unroll
    for (int nt = 0; nt < 6; ++nt) {
      int col = nt * 16 + mrow;
      float bias = merge_b[col];
      f32x4 acc = {bias, bias, bias, bias};
#pragma unroll
      for (int kt = 0; kt < 3; ++kt) {
        bf16x8 bf = *(const bf16x8*)(wsw + (size_t)(54 + nt * 3 + kt) * 512 + lane * 8);
        acc = __builtin_amdgcn_mfma_f32_16x16x32_bf16(aM[kt], bf, acc, 0, 0, 0);
      }
#pragma unroll
      for (int r = 0; r < 4; ++r) R[(tokb + r) * KPAD + col] = f2bf(acc[r]);
    }
  }
  __syncthreads();  // (5) msg2 complete

  // P5: hmid = gelu(X@w1a + msg2@w1b + b1) -> R[6656 + tok*KPAD + col]
  // X A-fragments come from registers (aX) -- no LDS re-read.
  {
    bf16x8 aM2[3];
#pragma unroll
    for (int kt = 0; kt < 3; ++kt) aM2[kt] = *(const bf16x8*)(R + arow + kt * 32);
#pragma unroll
    for (int nt = 0; nt < 6; ++nt) {
      int col = nt * 16 + mrow;
      float bias = b1[col];
      f32x4 acc = {bias, bias, bias, bias};
#pragma unroll
      for (int kt = 0; kt < 3; ++kt) {
        bf16x8 bf = *(const bf16x8*)(wsw + (size_t)(72 + nt * 3 + kt) * 512 + lane * 8);
        acc = __builtin_amdgcn_mfma_f32_16x16x32_bf16(aX[kt], bf, acc, 0, 0, 0);
      }
#pragma unroll
      for (int kt = 0; kt < 3; ++kt) {
        bf16x8 bf = *(const bf16x8*)(wsw + (size_t)(90 + nt * 3 + kt) * 512 + lane * 8);
        acc = __builtin_amdgcn_mfma_f32_16x16x32_bf16(aM2[kt], bf, acc, 0, 0, 0);
      }
#pragma unroll
      for (int r = 0; r < 4; ++r) {
        float h = acc[r];
        float gel = 0.5f * h * (1.0f + erff(h * 0.70710678118654752f));
        R[6656 + (tokb + r) * KPAD + col] = f2bf(gel);
      }
    }
  }
  __syncthreads();  // (6) P6's out region overwrites other waves' msg2:
                    // all P5 msg2 reads must complete first

  // P6: out = hmid @ w2 + b2 -> R[col*OPAD + tok]  (over dead msg region)
  {
    bf16x8 aH[3];
#pragma unroll
    for (int kt = 0; kt < 3; ++kt) aH[kt] = *(const bf16x8*)(R + 6656 + arow + kt * 32);
#pragma unroll
    for (int nt = 0; nt < 6; ++nt) {
      int col = nt * 16 + mrow;
      float bias = b2[col];
      f32x4 acc = {bias, bias, bias, bias};
#pragma unroll
      for (int kt = 0; kt < 3; ++kt) {
        bf16x8 bf = *(const bf16x8*)(wsw + (size_t)(108 + nt * 3 + kt) * 512 + lane * 8);
        acc = __builtin_amdgcn_mfma_f32_16x16x32_bf16(aH[kt], bf, acc, 0, 0, 0);
      }
#pragma unroll
      for (int r = 0; r < 4; ++r) R[col * OPAD + tokb + r] = f2bf(acc[r]);
    }
  }
  __syncthreads();  // (7) out region read cross-wave in P7

  // P7: coalesced float4 store along t
  for (int i = tid; i < 1536; i += 256) {
    int q = i & 3, dw = (i >> 2) & 1, dh = (i >> 3) & 1, c = i >> 4;
    float vv[4];
#pragma unroll
    for (int j = 0; j < 4; ++j) {
      int tl = q * 4 + j;
      vv[j] = bf2f(R[c * OPAD + (tl >> 1) * 8 + dh * 4 + dw * 2 + (tl & 1)]);
    }
    float4 v = {vv[0], vv[1], vv[2], vv[3]};
    size_t g = ((((size_t)b * 96 + c) * 64 + h0 * 2 + dh) * 64 + w0 * 2 + dw) * 64 + t0 * 16 + q * 4;
    *(float4*)(out + g) = v;
  }
}

extern "C" void kernel_launch(void* const* d_in, const int* in_sizes, int n_in,
                              void* d_out, int out_size, void* d_ws, size_t ws_size,
                              hipStream_t stream) {
  const float* x = (const float*)d_in[0];
  const float* qkv_w = (const float*)d_in[1];
  const float* qkv_b = (const float*)d_in[2];
  const float* merge_w = (const float*)d_in[3];
  const float* merge_b = (const float*)d_in[4];
  const float* w1 = (const float*)d_in[5];
  const float* b1 = (const float*)d_in[6];
  const float* w2 = (const float*)d_in[7];
  const float* b2 = (const float*)d_in[8];
  ushort* wsw = (ushort*)d_ws;  // needs 129024 B
  swizzle_w<<<dim3(32), dim3(256), 0, stream>>>(qkv_w, merge_w, w1, w2, wsw);
  // grid: B(2) x h0(32) x w0(32) x t0(4) = 8192 blocks
  swin_mfma<<<dim3(8192), dim3(256), 0, stream>>>(
      x, qkv_b, merge_b, b1, b2, wsw, (float*)d_out);
}

// Round 8
// 553.308 us; speedup vs baseline: 1.1695x; 1.0053x over previous
//
#include <hip/hip_runtime.h>
#include <math.h>

typedef short bf16x8 __attribute__((ext_vector_type(8)));
typedef float f32x4 __attribute__((ext_vector_type(4)));

#define SCALE_Q 0.28867513459481287f  // 1/sqrt(12)

__device__ __forceinline__ ushort f2bf(float f) {
  union { float f; unsigned int i; } v; v.f = f;
  unsigned int x = v.i;
  return (ushort)((x + 0x7fffu + ((x >> 16) & 1u)) >> 16);  // RNE
}
__device__ __forceinline__ float bf2f(ushort u) {
  union { unsigned int i; float f; } v; v.i = ((unsigned int)u) << 16; return v.f;
}
// packed helpers: dword holds 2 bf16 (lo = even tok, hi = odd tok)
__device__ __forceinline__ float bfLo(unsigned int d) {
  union { unsigned int i; float f; } v; v.i = d << 16; return v.f;
}
__device__ __forceinline__ float bfHi(unsigned int d) {
  union { unsigned int i; float f; } v; v.i = d & 0xffff0000u; return v.f;
}

// ---------------- pre-kernel: swizzle weights to B-fragment tiles ----------
// tile = 16 cols x 32 k = 64 lanes x 8 bf16 (lane holds B[k0+(l>>4)*8+j][n0+(l&15)])
// NEW tile map (108 tiles x 1024 B = 110592 B):
//   [0,54)   qkv (3 chunks x 6nt x 3kt); Q chunk (tiles 0..17) pre-scaled by 1/sqrt(12)
//   [54,72)  w1a (w1 rows 0..95, the X path)
//   [72,90)  Wfold = merge_w @ w1b  (fp32 fold computed here; msg path)
//   [90,108) w2
// foldb (96 f32 = b1 + merge_b @ w1b) at byte offset 110592. Total 110976 B.
__global__ void swizzle_w(const float* __restrict__ qkv_w,
                          const float* __restrict__ merge_w,
                          const float* __restrict__ merge_b,
                          const float* __restrict__ w1,
                          const float* __restrict__ b1,
                          const float* __restrict__ w2,
                          ushort* __restrict__ ws) {
  int g = blockIdx.x * 256 + threadIdx.x;
  if (g < 6912) {  // 108 tiles * 64 lanes
    int tile = g >> 6, lane = g & 63;
    float vals[8];
    if (tile < 54) {
      int rem = tile % 18;
      int c0 = (tile / 18) * 96 + (rem / 3) * 16, k0 = (rem % 3) * 32;
      int n = c0 + (lane & 15), kb = k0 + (lane >> 4) * 8;
      float s = (tile < 18) ? SCALE_Q : 1.0f;  // fold softmax scale into Q
#pragma unroll
      for (int j = 0; j < 8; ++j) vals[j] = qkv_w[(size_t)(kb + j) * 288 + n] * s;
    } else if (tile < 72) {
      int rem = tile - 54;
      int c0 = (rem / 3) * 16, k0 = (rem % 3) * 32;
      int n = c0 + (lane & 15), kb = k0 + (lane >> 4) * 8;
#pragma unroll
      for (int j = 0; j < 8; ++j) vals[j] = w1[(size_t)(kb + j) * 96 + n];
    } else if (tile < 90) {
      // Wfold[k][n] = sum_m merge_w[k][m] * w1[(96+m)][n]  (fp32)
      int rem = tile - 72;
      int c0 = (rem / 3) * 16, k0 = (rem % 3) * 32;
      int n = c0 + (lane & 15), kb = k0 + (lane >> 4) * 8;
      float acc[8] = {0, 0, 0, 0, 0, 0, 0, 0};
      for (int m = 0; m < 96; ++m) {
        float wr = w1[(size_t)(96 + m) * 96 + n];
#pragma unroll
        for (int j = 0; j < 8; ++j) acc[j] += merge_w[(size_t)(kb + j) * 96 + m] * wr;
      }
#pragma unroll
      for (int j = 0; j < 8; ++j) vals[j] = acc[j];
    } else {
      int rem = tile - 90;
      int c0 = (rem / 3) * 16, k0 = (rem % 3) * 32;
      int n = c0 + (lane & 15), kb = k0 + (lane >> 4) * 8;
#pragma unroll
      for (int j = 0; j < 8; ++j) vals[j] = w2[(size_t)(kb + j) * 96 + n];
    }
    ushort tmp[8];
#pragma unroll
    for (int j = 0; j < 8; ++j) tmp[j] = f2bf(vals[j]);
    *(uint4*)(ws + tile * 512 + lane * 8) = *(const uint4*)tmp;
  } else if (g < 7008) {  // foldb[n] = b1[n] + sum_m merge_b[m]*w1b[m][n]
    int n = g - 6912;
    float s = b1[n];
    for (int m = 0; m < 96; ++m) s += merge_b[m] * w1[(size_t)(96 + m) * 96 + n];
    ((float*)(ws + 55296))[n] = s;
  }
}

// ---------------- main fused kernel ----------------------------------------
// block: 64 tokens = (2h x 2w) x 16t = 8 windows along t. 4 waves, wave w owns
// tokens [16w,16w+16). Weights direct from global (wsw, L2-resident).
// X staged into R (dead before P2), aX held in registers through P5.
// CHANGE vs round 7: merge matmul (old P4) eliminated by the Wfold
// pre-computation; softmax scale folded into Q tiles. One fewer phase,
// one fewer barrier, 18 fewer MFMA + 54 fewer weight loads per wave.
#define KPAD 104
#define QPAD 68   // QKV [col 0..287][tok]; 68*2B=136B stride; all P3 read
                  // offsets are multiples of 4 ushorts (8B) -> uint2-safe
#define OPAD 65   // out [col 0..95][tok] stride
__global__ __launch_bounds__(256, 3) void swin_mfma(
    const float* __restrict__ x,
    const float* __restrict__ qkv_b, const float* __restrict__ b2,
    const ushort* __restrict__ wsw, float* __restrict__ out) {
  __shared__ __align__(16) ushort R[288 * QPAD];   // 39168 B: X -> QKV -> msg/hmid/out

  const int tid = threadIdx.x, bid = blockIdx.x;
  const int t0 = bid & 3, w0 = (bid >> 2) & 31, h0 = (bid >> 7) & 31, b = bid >> 12;
  const int lane = tid & 63, wave = tid >> 6;
  const int mrow = lane & 15, quad = lane >> 4;
  const int arow = (wave * 16 + mrow) * KPAD + quad * 8;  // A-frag base (elems)
  const int tokb = wave * 16 + quad * 4;                  // C-frag row base
  const float* foldb = (const float*)(wsw + 55296);

  // P1: x -> R[tok*KPAD + c] bf16 (coalesced float4 along t); R dead until P2
  for (int i = tid; i < 1536; i += 256) {
    int q = i & 3, dw = (i >> 2) & 1, dh = (i >> 3) & 1, c = i >> 4;
    size_t g = ((((size_t)b * 96 + c) * 64 + h0 * 2 + dh) * 64 + w0 * 2 + dw) * 64 + t0 * 16 + q * 4;
    float4 v = *(const float4*)(x + g);
    float vv[4] = {v.x, v.y, v.z, v.w};
    int base = dh * 4 + dw * 2;
#pragma unroll
    for (int j = 0; j < 4; ++j) {
      int tl = q * 4 + j;
      R[((tl >> 1) * 8 + base + (tl & 1)) * KPAD + c] = f2bf(vv[j]);
    }
  }
  __syncthreads();  // (1a) X staged cross-thread

  bf16x8 aX[3];     // held in registers through P5
#pragma unroll
  for (int kt = 0; kt < 3; ++kt)
    aX[kt] = *(const bf16x8*)(R + arow + kt * 32);
  __syncthreads();  // (1b) ALL waves' aX reads done before QKV overwrites R

  // P2: QKV (3 chunks of 96 cols) -> R[col][tok] stride QPAD
  for (int cn = 0; cn < 3; ++cn) {
#pragma unroll
    for (int nt = 0; nt < 6; ++nt) {
      int col = cn * 96 + nt * 16 + mrow;
      float bias = qkv_b[col];
      if (cn == 0) bias *= SCALE_Q;  // Q weights are pre-scaled; scale bias too
      f32x4 acc = {bias, bias, bias, bias};
#pragma unroll
      for (int kt = 0; kt < 3; ++kt) {
        bf16x8 bf = *(const bf16x8*)(wsw + (size_t)(cn * 18 + nt * 3 + kt) * 512 + lane * 8);
        acc = __builtin_amdgcn_mfma_f32_16x16x32_bf16(aX[kt], bf, acc, 0, 0, 0);
      }
#pragma unroll
      for (int r = 0; r < 4; ++r) R[col * QPAD + tokb + r] = f2bf(acc[r]);
    }
  }
  __syncthreads();  // (2) QKV complete

  // P3: attention. thread = (win, head, 2 query rows). Q cols 0..95, K 96.., V 192..
  // Packed reads: tok pairs (2t, 2t+1) share one dword (lo=even, hi=odd).
  // Q already carries the 1/sqrt(12) scale (folded into weights/bias).
  {
    const int win = tid >> 5, head = (tid >> 2) & 7, r2 = (tid & 3) * 2;
    const ushort* Qb = R + (head * 12) * QPAD + win * 8;
    const ushort* Kb = R + (96 + head * 12) * QPAD + win * 8;
    const ushort* Vb = R + (192 + head * 12) * QPAD + win * 8;
    float q0[12], q1[12];
#pragma unroll
    for (int d = 0; d < 12; ++d) {
      unsigned int qq = *(const unsigned int*)(Qb + d * QPAD + r2);  // rows r2,r2+1
      q0[d] = bfLo(qq);
      q1[d] = bfHi(qq);
    }
    float s0[8] = {0, 0, 0, 0, 0, 0, 0, 0}, s1[8] = {0, 0, 0, 0, 0, 0, 0, 0};
#pragma unroll
    for (int d = 0; d < 12; ++d) {  // K column d: all 8 window toks in 2 b64s
      uint2 ka = *(const uint2*)(Kb + d * QPAD);
      uint2 kc = *(const uint2*)(Kb + d * QPAD + 4);
      float kf[8] = {bfLo(ka.x), bfHi(ka.x), bfLo(ka.y), bfHi(ka.y),
                     bfLo(kc.x), bfHi(kc.x), bfLo(kc.y), bfHi(kc.y)};
#pragma unroll
      for (int m = 0; m < 8; ++m) { s0[m] += q0[d] * kf[m]; s1[m] += q1[d] * kf[m]; }
    }
    float mx0 = fmaxf(fmaxf(fmaxf(s0[0], s0[1]), fmaxf(s0[2], s0[3])),
                      fmaxf(fmaxf(s0[4], s0[5]), fmaxf(s0[6], s0[7])));
    float mx1 = fmaxf(fmaxf(fmaxf(s1[0], s1[1]), fmaxf(s1[2], s1[3])),
                      fmaxf(fmaxf(s1[4], s1[5]), fmaxf(s1[6], s1[7])));
    float sum0 = 0.f, sum1 = 0.f;
#pragma unroll
    for (int m = 0; m < 8; ++m) {
      s0[m] = __expf(s0[m] - mx0); sum0 += s0[m];
      s1[m] = __expf(s1[m] - mx1); sum1 += s1[m];
    }
    float inv0 = 1.0f / sum0, inv1 = 1.0f / sum1;
    float o0[12], o1[12];
#pragma unroll
    for (int d = 0; d < 12; ++d) {  // V column d, normalize at the end
      uint2 va = *(const uint2*)(Vb + d * QPAD);
      uint2 vc = *(const uint2*)(Vb + d * QPAD + 4);
      float vf[8] = {bfLo(va.x), bfHi(va.x), bfLo(va.y), bfHi(va.y),
                     bfLo(vc.x), bfHi(vc.x), bfLo(vc.y), bfHi(vc.y)};
      float a0 = 0.f, a1 = 0.f;
#pragma unroll
      for (int m = 0; m < 8; ++m) { a0 += s0[m] * vf[m]; a1 += s1[m] * vf[m]; }
      o0[d] = a0 * inv0; o1[d] = a1 * inv1;
    }
    __syncthreads();  // (3) ALL QKV reads complete before msg overwrites R
    int tr = win * 8 + r2;
#pragma unroll
    for (int d = 0; d < 12; ++d) {
      R[tr * KPAD + head * 12 + d] = f2bf(o0[d]);
      R[(tr + 1) * KPAD + head * 12 + d] = f2bf(o1[d]);
    }
  }
  __syncthreads();  // (4) msg complete

  // P5: hmid = gelu(X@w1a + msg@Wfold + foldb) -> R[6656 + tok*KPAD + col]
  // (merge matmul folded into Wfold; X frags from registers, msg frags are
  //  this wave's own rows)
  {
    bf16x8 aM2[3];
#pragma unroll
    for (int kt = 0; kt < 3; ++kt) aM2[kt] = *(const bf16x8*)(R + arow + kt * 32);
#pragma unroll
    for (int nt = 0; nt < 6; ++nt) {
      int col = nt * 16 + mrow;
      float bias = foldb[col];
      f32x4 acc = {bias, bias, bias, bias};
#pragma unroll
      for (int kt = 0; kt < 3; ++kt) {
        bf16x8 bf = *(const bf16x8*)(wsw + (size_t)(54 + nt * 3 + kt) * 512 + lane * 8);
        acc = __builtin_amdgcn_mfma_f32_16x16x32_bf16(aX[kt], bf, acc, 0, 0, 0);
      }
#pragma unroll
      for (int kt = 0; kt < 3; ++kt) {
        bf16x8 bf = *(const bf16x8*)(wsw + (size_t)(72 + nt * 3 + kt) * 512 + lane * 8);
        acc = __builtin_amdgcn_mfma_f32_16x16x32_bf16(aM2[kt], bf, acc, 0, 0, 0);
      }
#pragma unroll
      for (int r = 0; r < 4; ++r) {
        float h = acc[r];
        float gel = 0.5f * h * (1.0f + erff(h * 0.70710678118654752f));
        R[6656 + (tokb + r) * KPAD + col] = f2bf(gel);
      }
    }
  }
  __syncthreads();  // (5) P6's out region overwrites other waves' msg:
                    // all P5 msg reads must complete first

  // P6: out = hmid @ w2 + b2 -> R[col*OPAD + tok]  (over dead msg region)
  {
    bf16x8 aH[3];
#pragma unroll
    for (int kt = 0; kt < 3; ++kt) aH[kt] = *(const bf16x8*)(R + 6656 + arow + kt * 32);
#pragma unroll
    for (int nt = 0; nt < 6; ++nt) {
      int col = nt * 16 + mrow;
      float bias = b2[col];
      f32x4 acc = {bias, bias, bias, bias};
#pragma unroll
      for (int kt = 0; kt < 3; ++kt) {
        bf16x8 bf = *(const bf16x8*)(wsw + (size_t)(90 + nt * 3 + kt) * 512 + lane * 8);
        acc = __builtin_amdgcn_mfma_f32_16x16x32_bf16(aH[kt], bf, acc, 0, 0, 0);
      }
#pragma unroll
      for (int r = 0; r < 4; ++r) R[col * OPAD + tokb + r] = f2bf(acc[r]);
    }
  }
  __syncthreads();  // (6) out region read cross-wave in P7

  // P7: coalesced float4 store along t
  for (int i = tid; i < 1536; i += 256) {
    int q = i & 3, dw = (i >> 2) & 1, dh = (i >> 3) & 1, c = i >> 4;
    float vv[4];
#pragma unroll
    for (int j = 0; j < 4; ++j) {
      int tl = q * 4 + j;
      vv[j] = bf2f(R[c * OPAD + (tl >> 1) * 8 + dh * 4 + dw * 2 + (tl & 1)]);
    }
    float4 v = {vv[0], vv[1], vv[2], vv[3]};
    size_t g = ((((size_t)b * 96 + c) * 64 + h0 * 2 + dh) * 64 + w0 * 2 + dw) * 64 + t0 * 16 + q * 4;
    *(float4*)(out + g) = v;
  }
}

extern "C" void kernel_launch(void* const* d_in, const int* in_sizes, int n_in,
                              void* d_out, int out_size, void* d_ws, size_t ws_size,
                              hipStream_t stream) {
  const float* x = (const float*)d_in[0];
  const float* qkv_w = (const float*)d_in[1];
  const float* qkv_b = (const float*)d_in[2];
  const float* merge_w = (const float*)d_in[3];
  const float* merge_b = (const float*)d_in[4];
  const float* w1 = (const float*)d_in[5];
  const float* b1 = (const float*)d_in[6];
  const float* w2 = (const float*)d_in[7];
  const float* b2 = (const float*)d_in[8];
  ushort* wsw = (ushort*)d_ws;  // needs 110976 B
  // 7008 work items: 108 tiles x 64 lanes + 96 foldb
  swizzle_w<<<dim3(28), dim3(256), 0, stream>>>(qkv_w, merge_w, merge_b, w1, b1, w2, wsw);
  // grid: B(2) x h0(32) x w0(32) x t0(4) = 8192 blocks
  swin_mfma<<<dim3(8192), dim3(256), 0, stream>>>(
      x, qkv_b, b2, wsw, (float*)d_out);
}